// Round 7
// baseline (426.361 us; speedup 1.0000x reference)
//
#include <hip/hip_runtime.h>
#include <hip/hip_bf16.h>
#include <math.h>

// ShellConv on MI355X.
//  knn(+stats1): top-32 KNN (exact top_k order) -> idx, local, BN1 partials
//  fold1       : BN(3ch) folded into dense1 -> W1p,c1p
//  stats2/fold2: BN(32ch) of h1 folded into dense2 -> W2p,c2p
//  h2pool      : h1->h2 (64ch) + maxpool K/4 -> xp[..][0:64]
//  gatherpool  : gather prev (128ch) + maxpool -> xp[..][64:192] (XCD-swizzled)
//  stats3/finalize3/fold3: BN(192ch) folded into conv -> frag-packed bf16
//                hi/lo weights Wh/Wl + bcp
//  conv        : MFMA GEMM 16384x768 @ 768x256 (bf16x3 split-fp32) -> out
// R1: monolithic pool spilled (VGPR=256, 2.4 GB scratch) -> split kernels.
// R2: stats atomics (65K RMWs on 8 lines) cost 315 us -> block partials.
// R3: knn u32 butterflies + ballot/ffs tie-resolve.
// R4: fp32 VALU conv 159us -> bf16x3 MFMA (C = Ah*Bh + Ah*Bl + Al*Bh), ~25us.
// R5: knn per-column top-2 buffers (rescan only on 3rd+ extraction, E~1/q).
// R6 lesson: stats3 at 128 blocks left half the GPU idle streaming 50 MB
//     (+25 us) -> back to 512. knn now VALU-throughput-bound (80% busy) ->
//     cut instructions: ||p||^2 precomputed in LDS at staging, exact
//     fma(2,dot,-qq) contraction, incremental ~n code.

#define B_   8
#define N_   4096
#define M_   2048
#define K_   32
#define F1_  128
#define F2_  256
#define CIN_ 192
#define NROWS_ (B_*M_*K_)      // 524288
#define NQ_    (B_*M_)         // 16384
#define EPS_ 1e-5f

#define S2_BLK 512
#define S3_BLK 512

typedef __attribute__((ext_vector_type(8))) short bf16x8;
typedef __attribute__((ext_vector_type(4))) float f32x4;

// order-preserving u32 key of d = fma(2, q.p, -||q||^2) - ||p||^2.
// mul_rn(2,dot) is EXACT (exponent increment), so fma(2,dot,-qq) rounds the
// same value sub(mul(2,dot),qq) rounds -> bit-identical to the reference's
// 2*dot - qq - pp chain.
__device__ __forceinline__ unsigned int fkey_pp(float qx, float qy, float qz, float qq,
                                                float x, float y, float z, float pv) {
    float dot = fmaf(qz, z, fmaf(qy, y, __fmul_rn(qx, x)));
    float d   = __fsub_rn(fmaf(2.0f, dot, -qq), pv);
    unsigned int u = __float_as_uint(d);
    return u ^ ((unsigned int)((int)u >> 31) | 0x80000000u);
}

// split-fp32 -> bf16 hi (truncate) and lo (truncated residual), 2-packed.
__device__ __forceinline__ unsigned int pack_hi(float f0, float f1) {
    return (__float_as_uint(f0) >> 16) | (__float_as_uint(f1) & 0xFFFF0000u);
}
__device__ __forceinline__ unsigned int pack_lo(float f0, float f1) {
    float r0 = f0 - __uint_as_float(__float_as_uint(f0) & 0xFFFF0000u);
    float r1 = f1 - __uint_as_float(__float_as_uint(f1) & 0xFFFF0000u);
    return (__float_as_uint(r0) >> 16) | (__float_as_uint(r1) & 0xFFFF0000u);
}

// ---------------- knn: 8 queries/block, padded LDS, top-2 column buffers ----
// LDS: point n = col + 64*slot at [slot*65 + col]; pp precomputed at staging.
// pass1 (col=lane): lane stride 1 -> conflict-free; rescan (slot=lane):
// stride 65 = 1 mod 32 -> conflict-free.
__global__ __launch_bounds__(512) void knn_kernel(const float* __restrict__ points,
                                                  const float* __restrict__ queries,
                                                  int* __restrict__ idx_out,
                                                  float* __restrict__ local_out,
                                                  float* __restrict__ part1) {
    __shared__ float px[4160], py[4160], pz[4160], pp[4160];   // 66,560 B
    __shared__ float acc1[8][6];
    const int q0 = blockIdx.x * 8;
    const int b  = q0 >> 11;             // 2048 queries per batch
    const float* pb = points + (size_t)b * N_ * 3;
    for (int p = threadIdx.x; p < N_; p += 512) {
        const float* g = pb + p * 3;
        float x = g[0], y = g[1], z = g[2];
        int a = (p >> 6) * 65 + (p & 63);
        px[a] = x; py[a] = y; pz[a] = z;
        pp[a] = __fadd_rn(__fadd_rn(__fmul_rn(x, x), __fmul_rn(y, y)), __fmul_rn(z, z));
    }
    __syncthreads();

    const int lane = threadIdx.x & 63;
    const int wid  = threadIdx.x >> 6;
    const int q = q0 + wid;
    const float qx = queries[q * 3 + 0];
    const float qy = queries[q * 3 + 1];
    const float qz = queries[q * 3 + 2];
    const float qq = __fadd_rn(__fadd_rn(__fmul_rn(qx, qx), __fmul_rn(qy, qy)), __fmul_rn(qz, qz));

    // pass 1: per-column top-2 (u64 keys; guarded sorted insert).
    // klo = ~(lane + 64j) tracked incrementally (= ~lane - 64j).
    unsigned long long m0 = 0ull, m1 = 0ull;
    unsigned int klo = ~(unsigned int)lane;
    #pragma unroll 8
    for (int j = 0; j < 64; ++j) {
        int a = j * 65 + lane;
        unsigned int fk = fkey_pp(qx, qy, qz, qq, px[a], py[a], pz[a], pp[a]);
        unsigned long long key = ((unsigned long long)fk << 32) | klo;
        klo -= 64u;
        if (key > m1) {
            unsigned long long lo = (key < m0) ? key : m0;
            m0 = (key > m0) ? key : m0;
            m1 = lo;
        }
    }

    unsigned long long takenT = 0ull;  // bit c: point (col c, slot lane) taken
    int sel_n = 0;
    const int rb = lane * 65;
    for (int r = 0; r < 32; ++r) {
        // global max of per-column bests (u32 fk), tie -> lowest candidate n
        unsigned int m_fk = (unsigned int)(m0 >> 32);
        unsigned int g = m_fk;
        #pragma unroll
        for (int off = 32; off; off >>= 1) {
            unsigned int o = __shfl_xor(g, off, 64);
            g = (o > g) ? o : g;
        }
        unsigned long long mk = __ballot(m_fk == g);
        unsigned int nstar;
        if (__popcll(mk) == 1) {                       // common case: unique max
            int src = __ffsll(mk) - 1;
            nstar = ~(unsigned int)__shfl((int)(unsigned int)m0, src, 64);
        } else {                                       // rare: fk tie across columns
            unsigned int nm = (m_fk == g) ? ~(unsigned int)m0 : 0xFFFFFFFFu;
            #pragma unroll
            for (int off = 32; off; off >>= 1) {
                unsigned int o = __shfl_xor(nm, off, 64);
                nm = (o < nm) ? o : nm;
            }
            nstar = nm;
        }
        if (lane == r) sel_n = (int)nstar;
        const int w  = nstar & 63;
        const int js = (int)(nstar >> 6);
        if (lane == js) takenT |= (1ull << w);
        // pop winner's buffer
        if (lane == w) { m0 = m1; m1 = 0ull; }
        // rescan only when column w is exhausted (expected ~1x per query)
        unsigned long long need = __ballot(lane == w && m0 == 0ull);
        if (need) {
            int a2 = rb + w;                           // slot=lane of column w
            unsigned int fk2 = fkey_pp(qx, qy, qz, qq, px[a2], py[a2], pz[a2], pp[a2]);
            if ((unsigned int)(takenT >> w) & 1u) fk2 = 0u;
            unsigned int g2 = fk2;
            #pragma unroll
            for (int off = 32; off; off >>= 1) {
                unsigned int o = __shfl_xor(g2, off, 64);
                g2 = (o > g2) ? o : g2;
            }
            unsigned long long mk2 = __ballot(fk2 == g2);
            int src2 = __ffsll(mk2) - 1;               // lowest slot = lowest n
            if (lane == w) {
                m0 = ((unsigned long long)g2 << 32)
                   | (unsigned int)~((unsigned int)w + ((unsigned int)src2 << 6));
            }
        }
    }

    // outputs + local coords; fused BN1 partial sums
    float vx = 0.f, vy = 0.f, vz = 0.f;
    if (lane < 32) {
        idx_out[q * K_ + lane] = sel_n;
        int a = (sel_n >> 6) * 65 + (sel_n & 63);
        vx = __fsub_rn(qx, px[a]);
        vy = __fsub_rn(qy, py[a]);
        vz = __fsub_rn(qz, pz[a]);
        size_t o = ((size_t)q * K_ + lane) * 3;
        local_out[o + 0] = vx; local_out[o + 1] = vy; local_out[o + 2] = vz;
    }
    float s0 = vx, s1 = vy, s2 = vz, s3 = vx*vx, s4 = vy*vy, s5 = vz*vz;
    #pragma unroll
    for (int off = 32; off; off >>= 1) {
        s0 += __shfl_xor(s0, off, 64); s1 += __shfl_xor(s1, off, 64);
        s2 += __shfl_xor(s2, off, 64); s3 += __shfl_xor(s3, off, 64);
        s4 += __shfl_xor(s4, off, 64); s5 += __shfl_xor(s5, off, 64);
    }
    if (lane == 0) { acc1[wid][0]=s0; acc1[wid][1]=s1; acc1[wid][2]=s2;
                     acc1[wid][3]=s3; acc1[wid][4]=s4; acc1[wid][5]=s5; }
    __syncthreads();
    if (threadIdx.x < 6) {
        float s = 0.f;
        #pragma unroll
        for (int i = 0; i < 8; ++i) s += acc1[i][threadIdx.x];
        part1[blockIdx.x * 8 + threadIdx.x] = s;
    }
}

// ---------------- fold1: reduce 2048 block partials + fold BN1 into dense1 ----
__global__ __launch_bounds__(256) void fold1_kernel(const float* __restrict__ part1,
                             const float* __restrict__ g1, const float* __restrict__ b1,
                             const float* __restrict__ W1, const float* __restrict__ c1,
                             float* __restrict__ W1p, float* __restrict__ c1p) {
    __shared__ float red[32][8];
    __shared__ float cs[8];
    const int t = threadIdx.x;          // 256
    const int c = t & 7, ch = t >> 3;   // ch 0..31
    float s = 0.f;
    for (int i = 0; i < 64; ++i) s += part1[(ch * 64 + i) * 8 + c];
    red[ch][c] = s;
    __syncthreads();
    if (t < 8) {
        float v = 0.f;
        #pragma unroll
        for (int i = 0; i < 32; ++i) v += red[i][t];
        cs[t] = v;
    }
    __syncthreads();
    if (t >= 32) return;
    const float inv_n = 1.0f / (float)NROWS_;
    float cacc = c1[t];
    #pragma unroll
    for (int c3 = 0; c3 < 3; ++c3) {
        float mean = cs[c3] * inv_n;
        float var  = cs[3 + c3] * inv_n - mean * mean;
        float sc   = g1[c3] / sqrtf(var + EPS_);
        float tc   = b1[c3] - mean * sc;
        float w    = W1[c3 * 32 + t];
        W1p[c3 * 32 + t] = sc * w;
        cacc += tc * w;
    }
    c1p[t] = cacc;
}

// ---------------- stats2: per-block partial sums of h1 ----------------
__global__ __launch_bounds__(256) void stats2_kernel(const float* __restrict__ local,
                                                     const float* __restrict__ W1p,
                                                     const float* __restrict__ c1p,
                                                     float* __restrict__ part2) {
    __shared__ float w[96], cb[32];
    __shared__ float red[4][64];
    if (threadIdx.x < 96) w[threadIdx.x] = W1p[threadIdx.x];
    if (threadIdx.x < 32) cb[threadIdx.x] = c1p[threadIdx.x];
    __syncthreads();
    float sum[32], sq[32];
    #pragma unroll
    for (int i = 0; i < 32; ++i) { sum[i] = 0.f; sq[i] = 0.f; }
    int tid = blockIdx.x * 256 + threadIdx.x;
    for (int r = tid; r < NROWS_; r += S2_BLK * 256) {
        float x = local[(size_t)r*3], y = local[(size_t)r*3+1], z = local[(size_t)r*3+2];
        #pragma unroll
        for (int f = 0; f < 32; ++f) {
            float h = fmaf(z, w[64 + f], fmaf(y, w[32 + f], fmaf(x, w[f], cb[f])));
            h = fmaxf(h, 0.0f);
            sum[f] += h; sq[f] += h * h;
        }
    }
    #pragma unroll
    for (int f = 0; f < 32; ++f) {
        #pragma unroll
        for (int off = 32; off; off >>= 1) {
            sum[f] += __shfl_xor(sum[f], off, 64);
            sq[f]  += __shfl_xor(sq[f], off, 64);
        }
    }
    int lane = threadIdx.x & 63, wid = threadIdx.x >> 6;
    if (lane == 0) {
        #pragma unroll
        for (int f = 0; f < 32; ++f) { red[wid][f] = sum[f]; red[wid][32 + f] = sq[f]; }
    }
    __syncthreads();
    if (threadIdx.x < 64) {
        part2[blockIdx.x * 64 + threadIdx.x] =
            red[0][threadIdx.x] + red[1][threadIdx.x] + red[2][threadIdx.x] + red[3][threadIdx.x];
    }
}

// ---------------- fold2: reduce part2 (2-way split) + fold BN2 into dense2 ----
__global__ void fold2_kernel(const float* __restrict__ part2,
                             const float* __restrict__ g2, const float* __restrict__ b2,
                             const float* __restrict__ W2, const float* __restrict__ c2,
                             float* __restrict__ W2p, float* __restrict__ c2p) {
    __shared__ float red2[2][64];
    __shared__ float cs[64];
    int t = threadIdx.x;               // 128 threads
    int f = t & 63, h = t >> 6;
    {
        float s = 0.f;
        #pragma unroll 8
        for (int i = h * (S2_BLK / 2); i < (h + 1) * (S2_BLK / 2); ++i)
            s += part2[i * 64 + f];
        red2[h][f] = s;
    }
    __syncthreads();
    if (t >= 64) return;
    cs[f] = red2[0][f] + red2[1][f];
    __syncthreads();
    const float inv_n = 1.0f / (float)NROWS_;
    float cacc = c2[f];
    for (int c = 0; c < 32; ++c) {
        float mean = cs[c] * inv_n;
        float var  = cs[32 + c] * inv_n - mean * mean;
        float sc   = g2[c] / sqrtf(var + EPS_);
        float tc   = b2[c] - mean * sc;
        float wv   = W2[c * 64 + f];
        W2p[c * 64 + f] = sc * wv;
        cacc += tc * wv;
    }
    c2p[f] = cacc;
}

// ---------------- h2pool: h1 -> h2 (64 ch) + maxpool -> xp[..][0:64] ----------------
__global__ __launch_bounds__(256) void h2pool_kernel(const float* __restrict__ local,
                                                     const float* __restrict__ W1p,
                                                     const float* __restrict__ c1p,
                                                     const float* __restrict__ W2p,
                                                     const float* __restrict__ c2p,
                                                     float* __restrict__ xp) {
    __shared__ float h1buf[4][32 * 32];
    const int lane = threadIdx.x & 63, wid = threadIdx.x >> 6;
    const int q = blockIdx.x * 4 + wid;

    float w2c[32];
    #pragma unroll 8
    for (int c = 0; c < 32; ++c) w2c[c] = W2p[c * 64 + lane];
    const float c2l = c2p[lane];

    const int f0 = lane & 31;
    const float wa = W1p[f0], wb = W1p[32 + f0], wc = W1p[64 + f0], cc = c1p[f0];
    float* hb = &h1buf[wid][0];
    #pragma unroll 2
    for (int i = 0; i < 16; ++i) {
        int t = lane + 64 * i;
        int k = t >> 5;
        size_t lo = ((size_t)q * K_ + k) * 3;
        float x = local[lo], y = local[lo + 1], z = local[lo + 2];
        float h = fmaf(z, wc, fmaf(y, wb, fmaf(x, wa, cc)));
        hb[t] = fmaxf(h, 0.0f);
    }
    __syncthreads();

    float pm[4] = {-INFINITY, -INFINITY, -INFINITY, -INFINITY};
    #pragma unroll 2
    for (int k = 0; k < 32; ++k) {
        const float* hk = &hb[k * 32];
        float acc = c2l;
        #pragma unroll
        for (int c = 0; c < 32; ++c) acc = fmaf(hk[c], w2c[c], acc);
        float h2 = fmaxf(acc, 0.0f);
        int g = k >> 3;
        pm[g] = fmaxf(pm[g], h2);
    }

    float* xq = xp + (size_t)q * 4 * CIN_;
    #pragma unroll
    for (int g = 0; g < 4; ++g) xq[g * CIN_ + lane] = pm[g];
}

// ---------------- gatherpool: prev gather + maxpool -> xp[..][64:192] --------
__global__ __launch_bounds__(256) void gatherpool_kernel(const int* __restrict__ idx,
                                                         const float* __restrict__ prev,
                                                         float* __restrict__ xp) {
    const int lane = threadIdx.x & 63, wid = threadIdx.x >> 6;
    const int bid = blockIdx.x;
    const int q = ((bid & 7) << 11) + ((bid >> 3) << 2) + wid;
    const int b = q >> 11;

    int iv = 0;
    if (lane < 32) iv = idx[q * K_ + lane];
    float p0[4] = {-INFINITY, -INFINITY, -INFINITY, -INFINITY};
    float p1[4] = {-INFINITY, -INFINITY, -INFINITY, -INFINITY};
    const float* pbase = prev + (size_t)b * N_ * F1_;
    #pragma unroll 8
    for (int k = 0; k < 32; ++k) {
        int row = __shfl(iv, k, 64);
        const float* pr = pbase + (size_t)row * F1_;
        float v0 = pr[lane];
        float v1 = pr[64 + lane];
        int g = k >> 3;
        p0[g] = fmaxf(p0[g], v0);
        p1[g] = fmaxf(p1[g], v1);
    }

    float* xq = xp + (size_t)q * 4 * CIN_;
    #pragma unroll
    for (int g = 0; g < 4; ++g) {
        xq[g * CIN_ + 64 + lane]  = p0[g];
        xq[g * CIN_ + 128 + lane] = p1[g];
    }
}

// ---------------- stats3: per-block partial channel sums of xp ----------------
__global__ __launch_bounds__(192) void stats3_kernel(const float* __restrict__ xp,
                                                     float* __restrict__ part3) {
    int c = threadIdx.x;            // 0..191
    int r0 = blockIdx.x * 128;      // 128 of 65536 d-rows
    float s = 0.f, sq = 0.f;
    #pragma unroll 4
    for (int i = 0; i < 128; ++i) {
        float v = xp[(size_t)(r0 + i) * CIN_ + c];
        s += v; sq += v * v;
    }
    part3[blockIdx.x * 384 + c]       = s;
    part3[blockIdx.x * 384 + 192 + c] = sq;
}

// ---------------- finalize3: reduce part3 -> stats3 ----------------
__global__ __launch_bounds__(384) void finalize3_kernel(const float* __restrict__ part3,
                                                        float* __restrict__ stats3) {
    int t = threadIdx.x;            // 0..383
    float s = 0.f;
    #pragma unroll 4
    for (int i = 0; i < S3_BLK; ++i) s += part3[i * 384 + t];
    stats3[t] = s;
}

// ---------------- fold3: BN3 into conv, emit MFMA-frag-packed bf16 hi/lo ----
__global__ __launch_bounds__(256) void fold3_kernel(const float* __restrict__ stats3,
                                                    const float* __restrict__ g3, const float* __restrict__ b3,
                                                    const float* __restrict__ Wc, const float* __restrict__ bc,
                                                    unsigned short* __restrict__ Wh,
                                                    unsigned short* __restrict__ Wl,
                                                    float* __restrict__ bcp) {
    const int o = blockIdx.x;
    const float inv_n = 1.0f / (float)(NQ_ * 4);
    __shared__ float red[256];
    float tacc = 0.f;
    for (int t = threadIdx.x; t < CIN_ * 4; t += 256) {
        int c = t >> 2, d = t & 3;
        float mean = stats3[c] * inv_n;
        float var  = stats3[192 + c] * inv_n - mean * mean;
        float sc   = g3[c] / sqrtf(var + EPS_);
        float tc   = b3[c] - mean * sc;
        float wv   = Wc[(size_t)o * (CIN_ * 4) + t];
        float w    = sc * wv;
        unsigned int u = __float_as_uint(w);
        float rr = w - __uint_as_float(u & 0xFFFF0000u);
        int f  = d * CIN_ + c;                 // GEMM k index
        int ks = f >> 5, j = f & 7, lg = (f >> 3) & 3;
        size_t fi = ((size_t)(ks * 16 + (o >> 4)) * 64 + (lg * 16 + (o & 15))) * 8 + j;
        Wh[fi] = (unsigned short)(u >> 16);
        Wl[fi] = (unsigned short)(__float_as_uint(rr) >> 16);
        tacc += tc * wv;
    }
    red[threadIdx.x] = tacc;
    __syncthreads();
    for (int s = 128; s; s >>= 1) {
        if (threadIdx.x < s) red[threadIdx.x] += red[threadIdx.x + s];
        __syncthreads();
    }
    if (threadIdx.x == 0) bcp[o] = bc[o] + red[0];
}

// ---------------- conv: MFMA GEMM 16384x768 @ 768x256, bf16x3 ----------------
__global__ __launch_bounds__(512) void conv_kernel(const float* __restrict__ xp,
                                                   const unsigned short* __restrict__ Wh,
                                                   const unsigned short* __restrict__ Wl,
                                                   const float* __restrict__ bcp,
                                                   float* __restrict__ out) {
    __shared__ __align__(16) unsigned short Ah_s[64 * 64];      // 8 KB
    __shared__ __align__(16) unsigned short Al_s[64 * 64];      // 8 KB
    __shared__ __align__(16) unsigned short Bh_s[2 * 16 * 64 * 8]; // 32 KB
    __shared__ __align__(16) unsigned short Bl_s[2 * 16 * 64 * 8]; // 32 KB

    const int tid  = threadIdx.x;
    const int lane = tid & 63;
    const int wid  = tid >> 6;
    const int wr   = wid >> 2;          // 0..1: 32-row half
    const int wc   = wid & 3;           // 0..3: 64-col quarter
    const int row0 = blockIdx.x * 64;

    f32x4 acc[2][4];
    #pragma unroll
    for (int i = 0; i < 2; ++i)
        #pragma unroll
        for (int n = 0; n < 4; ++n) acc[i][n] = (f32x4){0.f, 0.f, 0.f, 0.f};

    const int ar  = tid >> 3;
    const int akq = tid & 7;
    const int a_byte = ar * 128 + ((akq ^ (ar & 7)) << 4);
    const float* arow = xp + (size_t)(row0 + ar) * 768 + akq * 8;

    const int fr_row = lane & 15;
    const int fr_grp = lane >> 4;       // k-subgroup 0..3

    for (int ks2 = 0; ks2 < 12; ++ks2) {
        __syncthreads();
        {
            const float* p = arow + ks2 * 64;
            float4 v0 = *(const float4*)p;
            float4 v1 = *(const float4*)(p + 4);
            uint4 h4, l4;
            h4.x = pack_hi(v0.x, v0.y); h4.y = pack_hi(v0.z, v0.w);
            h4.z = pack_hi(v1.x, v1.y); h4.w = pack_hi(v1.z, v1.w);
            l4.x = pack_lo(v0.x, v0.y); l4.y = pack_lo(v0.z, v0.w);
            l4.z = pack_lo(v1.x, v1.y); l4.w = pack_lo(v1.z, v1.w);
            *(uint4*)((char*)Ah_s + a_byte) = h4;
            *(uint4*)((char*)Al_s + a_byte) = l4;
        }
        {
            const uint4* gh = (const uint4*)(Wh + (size_t)ks2 * 16384);
            const uint4* gl = (const uint4*)(Wl + (size_t)ks2 * 16384);
            uint4* lh = (uint4*)Bh_s;
            uint4* ll = (uint4*)Bl_s;
            #pragma unroll
            for (int i = 0; i < 4; ++i) {
                lh[tid + 512 * i] = gh[tid + 512 * i];
                ll[tid + 512 * i] = gl[tid + 512 * i];
            }
        }
        __syncthreads();
        #pragma unroll
        for (int ks = 0; ks < 2; ++ks) {
            bf16x8 ah[2], al[2];
            #pragma unroll
            for (int i = 0; i < 2; ++i) {
                int r = wr * 32 + i * 16 + fr_row;
                int slot = ks * 4 + fr_grp;
                int byte = r * 128 + ((slot ^ (r & 7)) << 4);
                ah[i] = *(const bf16x8*)((const char*)Ah_s + byte);
                al[i] = *(const bf16x8*)((const char*)Al_s + byte);
            }
            #pragma unroll
            for (int nt = 0; nt < 4; ++nt) {
                int bidx = ((ks * 16 + wc * 4 + nt) * 64 + lane) * 8;
                bf16x8 bh = *(const bf16x8*)(Bh_s + bidx);
                bf16x8 bl = *(const bf16x8*)(Bl_s + bidx);
                #pragma unroll
                for (int i = 0; i < 2; ++i) {
                    acc[i][nt] = __builtin_amdgcn_mfma_f32_16x16x32_bf16(ah[i], bh, acc[i][nt], 0, 0, 0);
                    acc[i][nt] = __builtin_amdgcn_mfma_f32_16x16x32_bf16(ah[i], bl, acc[i][nt], 0, 0, 0);
                    acc[i][nt] = __builtin_amdgcn_mfma_f32_16x16x32_bf16(al[i], bh, acc[i][nt], 0, 0, 0);
                }
            }
        }
    }

    float bias[4];
    #pragma unroll
    for (int nt = 0; nt < 4; ++nt) bias[nt] = bcp[wc * 64 + nt * 16 + fr_row];
    #pragma unroll
    for (int i = 0; i < 2; ++i) {
        #pragma unroll
        for (int nt = 0; nt < 4; ++nt) {
            int col = wc * 64 + nt * 16 + fr_row;
            #pragma unroll
            for (int rg = 0; rg < 4; ++rg) {
                int row = row0 + wr * 32 + i * 16 + fr_grp * 4 + rg;
                out[(size_t)row * F2_ + col] = fmaxf(acc[i][nt][rg] + bias[nt], 0.0f);
            }
        }
    }
}

extern "C" void kernel_launch(void* const* d_in, const int* in_sizes, int n_in,
                              void* d_out, int out_size, void* d_ws, size_t ws_size,
                              hipStream_t stream) {
    const float* points  = (const float*)d_in[0];
    const float* queries = (const float*)d_in[1];
    const float* prev    = (const float*)d_in[2];
    const float* g1 = (const float*)d_in[3];
    const float* b1 = (const float*)d_in[4];
    const float* W1 = (const float*)d_in[5];
    const float* c1 = (const float*)d_in[6];
    const float* g2 = (const float*)d_in[7];
    const float* b2 = (const float*)d_in[8];
    const float* W2 = (const float*)d_in[9];
    const float* c2 = (const float*)d_in[10];
    const float* g3 = (const float*)d_in[11];
    const float* b3 = (const float*)d_in[12];
    const float* Wc = (const float*)d_in[13];
    const float* bc = (const float*)d_in[14];
    float* out = (float*)d_out;

    // Workspace layout (~59.5 MB; aliases are stream-order-safe):
    char* ws = (char*)d_ws;
    size_t off_idx    = 0;                               // 2,097,152 B
    size_t off_local  = off_idx + (size_t)NQ_*K_*4;      // 6,291,456 B (dead after h2pool)
    size_t off_stats3 = off_local + (size_t)NROWS_*3*4;  // 4,096 B (384 f32)
    size_t off_W1p    = off_stats3 + 4096;               // 512 B
    size_t off_c1p    = off_W1p + 512;                   // 512 B
    size_t off_W2p    = off_c1p + 512;                   // 8,192 B
    size_t off_c2p    = off_W2p + 8192;                  // 512 B
    size_t off_Wt     = off_c2p + 512;                   // 786,432 B: Wh(393216)+Wl(393216)
    size_t off_bcp    = off_Wt + 786432;                 // 1,024 B
    size_t off_xp     = off_bcp + 1024;                  // 50,331,648 B

    int*   idx    = (int*)(ws + off_idx);
    float* local  = (float*)(ws + off_local);
    float* stats3 = (float*)(ws + off_stats3);
    float* W1p    = (float*)(ws + off_W1p);
    float* c1p    = (float*)(ws + off_c1p);
    float* W2p    = (float*)(ws + off_W2p);
    float* c2p    = (float*)(ws + off_c2p);
    unsigned short* Wh = (unsigned short*)(ws + off_Wt);
    unsigned short* Wl = (unsigned short*)(ws + off_Wt + 393216);
    float* bcp    = (float*)(ws + off_bcp);
    float* xp     = (float*)(ws + off_xp);
    // part1 (64 KB) + part2 (512*64 f32 = 128 KB) alias the Wh/Wl region:
    // consumed by fold1/fold2 BEFORE fold3 writes Wh/Wl.
    float* part1  = (float*)(ws + off_Wt);
    float* part2  = (float*)(ws + off_Wt + 65536);
    // part3 (512*384 f32 = 768 KB) aliases local: written by stats3 AFTER
    // h2pool's last read of local.
    float* part3  = (float*)(ws + off_local);

    knn_kernel<<<NQ_ / 8, 512, 0, stream>>>(points, queries, idx, local, part1);
    fold1_kernel<<<1, 256, 0, stream>>>(part1, g1, b1, W1, c1, W1p, c1p);
    stats2_kernel<<<S2_BLK, 256, 0, stream>>>(local, W1p, c1p, part2);
    fold2_kernel<<<1, 128, 0, stream>>>(part2, g2, b2, W2, c2, W2p, c2p);
    h2pool_kernel<<<NQ_ / 4, 256, 0, stream>>>(local, W1p, c1p, W2p, c2p, xp);
    gatherpool_kernel<<<NQ_ / 4, 256, 0, stream>>>(idx, prev, xp);
    stats3_kernel<<<S3_BLK, 192, 0, stream>>>(xp, part3);
    finalize3_kernel<<<1, 384, 0, stream>>>(part3, stats3);
    fold3_kernel<<<F2_, 256, 0, stream>>>(stats3, g3, b3, Wc, bc, Wh, Wl, bcp);
    conv_kernel<<<NQ_ / 64, 512, 0, stream>>>(xp, Wh, Wl, bcp, out);
}

// Round 10
// 405.191 us; speedup vs baseline: 1.0522x; 1.0522x over previous
//
#include <hip/hip_runtime.h>
#include <hip/hip_bf16.h>
#include <math.h>

// ShellConv on MI355X.
//  knn(+stats1): top-32 KNN (exact top_k order) -> idx, local, BN1 partials
//  fold1       : BN(3ch) folded into dense1 -> W1p,c1p
//  stats2/fold2: BN(32ch) of h1 folded into dense2 -> W2p,c2p
//  h2pool      : h1->h2 (64ch) + maxpool K/4 -> xp[..][0:64]
//  gatherpool  : gather prev (128ch) + maxpool -> xp[..][64:192] (XCD-swizzled)
//  stats3/finalize3/fold3: BN(192ch) folded into conv -> frag-packed bf16
//                hi/lo weights Wh/Wl + bcp
//  conv        : MFMA GEMM 16384x768 @ 768x256 (bf16x3 split-fp32) -> out
// R1: monolithic pool spilled (VGPR=256, 2.4 GB scratch) -> split kernels.
// R2: stats atomics (65K RMWs on 8 lines) cost 315 us -> block partials.
// R3: knn u32 butterflies + ballot/ffs tie-resolve.
// R4: fp32 VALU conv 159us -> bf16x3 MFMA (C = Ah*Bh + Ah*Bl + Al*Bh), ~25us.
// R5: knn per-column top-2 buffers (rescan only on 3rd+ extraction, E~1/q).
// R6: pp-in-LDS attempt.
// R7 lesson: pp-in-LDS (66.5 KB) dropped 3->2 blocks/CU (occ 57->42%,
//     VALUBusy 80->59%) and LOST 10us despite fewer ops. The <=53 KB LDS /
//     3-block budget is a hard constraint here. -> revert to 3 padded arrays,
//     keep fma(2,dot,-qq) contraction + incremental n; switch top-2 to u32
//     (fk,n) pairs (drop-on-fk-tie is exact: scan is n-ascending, equal-fk
//     items rank below the held one; 3rd+ extraction handled by rescan).
// R8/R9: infra failures (container / broker capacity), resubmitted unchanged.

#define B_   8
#define N_   4096
#define M_   2048
#define K_   32
#define F1_  128
#define F2_  256
#define CIN_ 192
#define NROWS_ (B_*M_*K_)      // 524288
#define NQ_    (B_*M_)         // 16384
#define EPS_ 1e-5f

#define S2_BLK 512
#define S3_BLK 512

typedef __attribute__((ext_vector_type(8))) short bf16x8;
typedef __attribute__((ext_vector_type(4))) float f32x4;

// order-preserving u32 key of d = fma(2, q.p, -||q||^2) - ||p||^2.
// mul_rn(2,dot) is EXACT (exponent bump), so fma(2,dot,-qq) rounds the same
// value sub(mul(2,dot),qq) rounds -> bit-identical to the reference chain.
// pp uses the reference's plain-add chain.
__device__ __forceinline__ unsigned int fkey(float qx, float qy, float qz, float qq,
                                             float x, float y, float z) {
    float dot = fmaf(qz, z, fmaf(qy, y, __fmul_rn(qx, x)));
    float pp  = __fadd_rn(__fadd_rn(__fmul_rn(x, x), __fmul_rn(y, y)), __fmul_rn(z, z));
    float d   = __fsub_rn(fmaf(2.0f, dot, -qq), pp);
    unsigned int u = __float_as_uint(d);
    return u ^ ((unsigned int)((int)u >> 31) | 0x80000000u);
}

// split-fp32 -> bf16 hi (truncate) and lo (truncated residual), 2-packed.
__device__ __forceinline__ unsigned int pack_hi(float f0, float f1) {
    return (__float_as_uint(f0) >> 16) | (__float_as_uint(f1) & 0xFFFF0000u);
}
__device__ __forceinline__ unsigned int pack_lo(float f0, float f1) {
    float r0 = f0 - __uint_as_float(__float_as_uint(f0) & 0xFFFF0000u);
    float r1 = f1 - __uint_as_float(__float_as_uint(f1) & 0xFFFF0000u);
    return (__float_as_uint(r0) >> 16) | (__float_as_uint(r1) & 0xFFFF0000u);
}

// ---------------- knn: 8 queries/block, padded LDS, u32 top-2 columns -------
// LDS: point n = col + 64*slot at [slot*65 + col]. pass1 (col=lane): lane
// stride 1 -> conflict-free; rescan (slot=lane): stride 65 = 1 mod 32 -> free.
// 49,920 B LDS -> 3 blocks/CU (24 waves) -- do not exceed ~53 KB (R7 lesson).
__global__ __launch_bounds__(512) void knn_kernel(const float* __restrict__ points,
                                                  const float* __restrict__ queries,
                                                  int* __restrict__ idx_out,
                                                  float* __restrict__ local_out,
                                                  float* __restrict__ part1) {
    __shared__ float px[4160], py[4160], pz[4160];   // 49,920 B
    __shared__ float acc1[8][6];
    const int q0 = blockIdx.x * 8;
    const int b  = q0 >> 11;             // 2048 queries per batch
    const float* pb = points + (size_t)b * N_ * 3;
    for (int p = threadIdx.x; p < N_; p += 512) {
        const float* g = pb + p * 3;
        int a = (p >> 6) * 65 + (p & 63);
        px[a] = g[0]; py[a] = g[1]; pz[a] = g[2];
    }
    __syncthreads();

    const int lane = threadIdx.x & 63;
    const int wid  = threadIdx.x >> 6;
    const int q = q0 + wid;
    const float qx = queries[q * 3 + 0];
    const float qy = queries[q * 3 + 1];
    const float qz = queries[q * 3 + 2];
    const float qq = __fadd_rn(__fadd_rn(__fmul_rn(qx, qx), __fmul_rn(qy, qy)), __fmul_rn(qz, qz));

    // pass 1: per-column top-2 as u32 (fk, n) pairs.
    // Scan is n-ascending, so on fk tie the held (lower-n) entry stays ahead
    // and the new item may only displace strictly-smaller fk -- exact top_k
    // order; 3rd-or-lower column ranks are recovered by rescan.
    unsigned int fk0 = 0u, fk1 = 0u, n0 = 0u, n1 = 0u;
    unsigned int n = (unsigned int)lane;
    #pragma unroll 8
    for (int j = 0; j < 64; ++j) {
        int a = j * 65 + lane;
        unsigned int fk = fkey(qx, qy, qz, qq, px[a], py[a], pz[a]);
        if (fk > fk1) {
            bool g0 = fk > fk0;
            fk1 = g0 ? fk0 : fk;  n1 = g0 ? n0 : n;
            fk0 = g0 ? fk  : fk0; n0 = g0 ? n  : n0;
        }
        n += 64u;
    }

    unsigned long long takenT = 0ull;  // bit c of lane s: point (col c, slot s) taken
    int sel_n = 0;
    const int rb = lane * 65;
    for (int r = 0; r < 32; ++r) {
        // global max of per-column bests, tie -> lowest n
        unsigned int g = fk0;
        #pragma unroll
        for (int off = 32; off; off >>= 1) {
            unsigned int o = __shfl_xor(g, off, 64);
            g = (o > g) ? o : g;
        }
        unsigned long long mk = __ballot(fk0 == g);
        unsigned int nstar;
        if (__popcll(mk) == 1) {                       // common case: unique max
            int src = __ffsll(mk) - 1;
            nstar = (unsigned int)__shfl((int)n0, src, 64);
        } else {                                       // rare: fk tie across columns
            unsigned int nm = (fk0 == g) ? n0 : 0xFFFFFFFFu;
            #pragma unroll
            for (int off = 32; off; off >>= 1) {
                unsigned int o = __shfl_xor(nm, off, 64);
                nm = (o < nm) ? o : nm;
            }
            nstar = nm;
        }
        if (lane == r) sel_n = (int)nstar;
        const int w  = nstar & 63;
        const int js = (int)(nstar >> 6);
        if (lane == js) takenT |= (1ull << w);
        // pop winner's buffer (stale n1 is harmless: fk1=0 never wins)
        if (lane == w) { fk0 = fk1; n0 = n1; fk1 = 0u; }
        // rescan only when column w is exhausted (expected ~1x per query)
        unsigned long long need = __ballot(lane == w && fk0 == 0u);
        if (need) {
            int a2 = rb + w;                           // slot=lane of column w
            unsigned int fk2 = fkey(qx, qy, qz, qq, px[a2], py[a2], pz[a2]);
            if ((unsigned int)(takenT >> w) & 1u) fk2 = 0u;
            unsigned int g2 = fk2;
            #pragma unroll
            for (int off = 32; off; off >>= 1) {
                unsigned int o = __shfl_xor(g2, off, 64);
                g2 = (o > g2) ? o : g2;
            }
            unsigned long long mk2 = __ballot(fk2 == g2);
            int src2 = __ffsll(mk2) - 1;               // lowest slot = lowest n
            if (lane == w) { fk0 = g2; n0 = (unsigned int)w + ((unsigned int)src2 << 6); }
        }
    }

    // outputs + local coords; fused BN1 partial sums
    float vx = 0.f, vy = 0.f, vz = 0.f;
    if (lane < 32) {
        idx_out[q * K_ + lane] = sel_n;
        int a = (sel_n >> 6) * 65 + (sel_n & 63);
        vx = __fsub_rn(qx, px[a]);
        vy = __fsub_rn(qy, py[a]);
        vz = __fsub_rn(qz, pz[a]);
        size_t o = ((size_t)q * K_ + lane) * 3;
        local_out[o + 0] = vx; local_out[o + 1] = vy; local_out[o + 2] = vz;
    }
    float s0 = vx, s1 = vy, s2 = vz, s3 = vx*vx, s4 = vy*vy, s5 = vz*vz;
    #pragma unroll
    for (int off = 32; off; off >>= 1) {
        s0 += __shfl_xor(s0, off, 64); s1 += __shfl_xor(s1, off, 64);
        s2 += __shfl_xor(s2, off, 64); s3 += __shfl_xor(s3, off, 64);
        s4 += __shfl_xor(s4, off, 64); s5 += __shfl_xor(s5, off, 64);
    }
    if (lane == 0) { acc1[wid][0]=s0; acc1[wid][1]=s1; acc1[wid][2]=s2;
                     acc1[wid][3]=s3; acc1[wid][4]=s4; acc1[wid][5]=s5; }
    __syncthreads();
    if (threadIdx.x < 6) {
        float s = 0.f;
        #pragma unroll
        for (int i = 0; i < 8; ++i) s += acc1[i][threadIdx.x];
        part1[blockIdx.x * 8 + threadIdx.x] = s;
    }
}

// ---------------- fold1: reduce 2048 block partials + fold BN1 into dense1 ----
__global__ __launch_bounds__(256) void fold1_kernel(const float* __restrict__ part1,
                             const float* __restrict__ g1, const float* __restrict__ b1,
                             const float* __restrict__ W1, const float* __restrict__ c1,
                             float* __restrict__ W1p, float* __restrict__ c1p) {
    __shared__ float red[32][8];
    __shared__ float cs[8];
    const int t = threadIdx.x;          // 256
    const int c = t & 7, ch = t >> 3;   // ch 0..31
    float s = 0.f;
    for (int i = 0; i < 64; ++i) s += part1[(ch * 64 + i) * 8 + c];
    red[ch][c] = s;
    __syncthreads();
    if (t < 8) {
        float v = 0.f;
        #pragma unroll
        for (int i = 0; i < 32; ++i) v += red[i][t];
        cs[t] = v;
    }
    __syncthreads();
    if (t >= 32) return;
    const float inv_n = 1.0f / (float)NROWS_;
    float cacc = c1[t];
    #pragma unroll
    for (int c3 = 0; c3 < 3; ++c3) {
        float mean = cs[c3] * inv_n;
        float var  = cs[3 + c3] * inv_n - mean * mean;
        float sc   = g1[c3] / sqrtf(var + EPS_);
        float tc   = b1[c3] - mean * sc;
        float w    = W1[c3 * 32 + t];
        W1p[c3 * 32 + t] = sc * w;
        cacc += tc * w;
    }
    c1p[t] = cacc;
}

// ---------------- stats2: per-block partial sums of h1 ----------------
__global__ __launch_bounds__(256) void stats2_kernel(const float* __restrict__ local,
                                                     const float* __restrict__ W1p,
                                                     const float* __restrict__ c1p,
                                                     float* __restrict__ part2) {
    __shared__ float w[96], cb[32];
    __shared__ float red[4][64];
    if (threadIdx.x < 96) w[threadIdx.x] = W1p[threadIdx.x];
    if (threadIdx.x < 32) cb[threadIdx.x] = c1p[threadIdx.x];
    __syncthreads();
    float sum[32], sq[32];
    #pragma unroll
    for (int i = 0; i < 32; ++i) { sum[i] = 0.f; sq[i] = 0.f; }
    int tid = blockIdx.x * 256 + threadIdx.x;
    for (int r = tid; r < NROWS_; r += S2_BLK * 256) {
        float x = local[(size_t)r*3], y = local[(size_t)r*3+1], z = local[(size_t)r*3+2];
        #pragma unroll
        for (int f = 0; f < 32; ++f) {
            float h = fmaf(z, w[64 + f], fmaf(y, w[32 + f], fmaf(x, w[f], cb[f])));
            h = fmaxf(h, 0.0f);
            sum[f] += h; sq[f] += h * h;
        }
    }
    #pragma unroll
    for (int f = 0; f < 32; ++f) {
        #pragma unroll
        for (int off = 32; off; off >>= 1) {
            sum[f] += __shfl_xor(sum[f], off, 64);
            sq[f]  += __shfl_xor(sq[f], off, 64);
        }
    }
    int lane = threadIdx.x & 63, wid = threadIdx.x >> 6;
    if (lane == 0) {
        #pragma unroll
        for (int f = 0; f < 32; ++f) { red[wid][f] = sum[f]; red[wid][32 + f] = sq[f]; }
    }
    __syncthreads();
    if (threadIdx.x < 64) {
        part2[blockIdx.x * 64 + threadIdx.x] =
            red[0][threadIdx.x] + red[1][threadIdx.x] + red[2][threadIdx.x] + red[3][threadIdx.x];
    }
}

// ---------------- fold2: reduce part2 (2-way split) + fold BN2 into dense2 ----
__global__ void fold2_kernel(const float* __restrict__ part2,
                             const float* __restrict__ g2, const float* __restrict__ b2,
                             const float* __restrict__ W2, const float* __restrict__ c2,
                             float* __restrict__ W2p, float* __restrict__ c2p) {
    __shared__ float red2[2][64];
    __shared__ float cs[64];
    int t = threadIdx.x;               // 128 threads
    int f = t & 63, h = t >> 6;
    {
        float s = 0.f;
        #pragma unroll 8
        for (int i = h * (S2_BLK / 2); i < (h + 1) * (S2_BLK / 2); ++i)
            s += part2[i * 64 + f];
        red2[h][f] = s;
    }
    __syncthreads();
    if (t >= 64) return;
    cs[f] = red2[0][f] + red2[1][f];
    __syncthreads();
    const float inv_n = 1.0f / (float)NROWS_;
    float cacc = c2[f];
    for (int c = 0; c < 32; ++c) {
        float mean = cs[c] * inv_n;
        float var  = cs[32 + c] * inv_n - mean * mean;
        float sc   = g2[c] / sqrtf(var + EPS_);
        float tc   = b2[c] - mean * sc;
        float wv   = W2[c * 64 + f];
        W2p[c * 64 + f] = sc * wv;
        cacc += tc * wv;
    }
    c2p[f] = cacc;
}

// ---------------- h2pool: h1 -> h2 (64 ch) + maxpool -> xp[..][0:64] ----------------
__global__ __launch_bounds__(256) void h2pool_kernel(const float* __restrict__ local,
                                                     const float* __restrict__ W1p,
                                                     const float* __restrict__ c1p,
                                                     const float* __restrict__ W2p,
                                                     const float* __restrict__ c2p,
                                                     float* __restrict__ xp) {
    __shared__ float h1buf[4][32 * 32];
    const int lane = threadIdx.x & 63, wid = threadIdx.x >> 6;
    const int q = blockIdx.x * 4 + wid;

    float w2c[32];
    #pragma unroll 8
    for (int c = 0; c < 32; ++c) w2c[c] = W2p[c * 64 + lane];
    const float c2l = c2p[lane];

    const int f0 = lane & 31;
    const float wa = W1p[f0], wb = W1p[32 + f0], wc = W1p[64 + f0], cc = c1p[f0];
    float* hb = &h1buf[wid][0];
    #pragma unroll 2
    for (int i = 0; i < 16; ++i) {
        int t = lane + 64 * i;
        int k = t >> 5;
        size_t lo = ((size_t)q * K_ + k) * 3;
        float x = local[lo], y = local[lo + 1], z = local[lo + 2];
        float h = fmaf(z, wc, fmaf(y, wb, fmaf(x, wa, cc)));
        hb[t] = fmaxf(h, 0.0f);
    }
    __syncthreads();

    float pm[4] = {-INFINITY, -INFINITY, -INFINITY, -INFINITY};
    #pragma unroll 2
    for (int k = 0; k < 32; ++k) {
        const float* hk = &hb[k * 32];
        float acc = c2l;
        #pragma unroll
        for (int c = 0; c < 32; ++c) acc = fmaf(hk[c], w2c[c], acc);
        float h2 = fmaxf(acc, 0.0f);
        int g = k >> 3;
        pm[g] = fmaxf(pm[g], h2);
    }

    float* xq = xp + (size_t)q * 4 * CIN_;
    #pragma unroll
    for (int g = 0; g < 4; ++g) xq[g * CIN_ + lane] = pm[g];
}

// ---------------- gatherpool: prev gather + maxpool -> xp[..][64:192] --------
__global__ __launch_bounds__(256) void gatherpool_kernel(const int* __restrict__ idx,
                                                         const float* __restrict__ prev,
                                                         float* __restrict__ xp) {
    const int lane = threadIdx.x & 63, wid = threadIdx.x >> 6;
    const int bid = blockIdx.x;
    const int q = ((bid & 7) << 11) + ((bid >> 3) << 2) + wid;
    const int b = q >> 11;

    int iv = 0;
    if (lane < 32) iv = idx[q * K_ + lane];
    float p0[4] = {-INFINITY, -INFINITY, -INFINITY, -INFINITY};
    float p1[4] = {-INFINITY, -INFINITY, -INFINITY, -INFINITY};
    const float* pbase = prev + (size_t)b * N_ * F1_;
    #pragma unroll 8
    for (int k = 0; k < 32; ++k) {
        int row = __shfl(iv, k, 64);
        const float* pr = pbase + (size_t)row * F1_;
        float v0 = pr[lane];
        float v1 = pr[64 + lane];
        int g = k >> 3;
        p0[g] = fmaxf(p0[g], v0);
        p1[g] = fmaxf(p1[g], v1);
    }

    float* xq = xp + (size_t)q * 4 * CIN_;
    #pragma unroll
    for (int g = 0; g < 4; ++g) {
        xq[g * CIN_ + 64 + lane]  = p0[g];
        xq[g * CIN_ + 128 + lane] = p1[g];
    }
}

// ---------------- stats3: per-block partial channel sums of xp ----------------
__global__ __launch_bounds__(192) void stats3_kernel(const float* __restrict__ xp,
                                                     float* __restrict__ part3) {
    int c = threadIdx.x;            // 0..191
    int r0 = blockIdx.x * 128;      // 128 of 65536 d-rows
    float s = 0.f, sq = 0.f;
    #pragma unroll 4
    for (int i = 0; i < 128; ++i) {
        float v = xp[(size_t)(r0 + i) * CIN_ + c];
        s += v; sq += v * v;
    }
    part3[blockIdx.x * 384 + c]       = s;
    part3[blockIdx.x * 384 + 192 + c] = sq;
}

// ---------------- finalize3: reduce part3 -> stats3 ----------------
__global__ __launch_bounds__(384) void finalize3_kernel(const float* __restrict__ part3,
                                                        float* __restrict__ stats3) {
    int t = threadIdx.x;            // 0..383
    float s = 0.f;
    #pragma unroll 4
    for (int i = 0; i < S3_BLK; ++i) s += part3[i * 384 + t];
    stats3[t] = s;
}

// ---------------- fold3: BN3 into conv, emit MFMA-frag-packed bf16 hi/lo ----
__global__ __launch_bounds__(256) void fold3_kernel(const float* __restrict__ stats3,
                                                    const float* __restrict__ g3, const float* __restrict__ b3,
                                                    const float* __restrict__ Wc, const float* __restrict__ bc,
                                                    unsigned short* __restrict__ Wh,
                                                    unsigned short* __restrict__ Wl,
                                                    float* __restrict__ bcp) {
    const int o = blockIdx.x;
    const float inv_n = 1.0f / (float)(NQ_ * 4);
    __shared__ float red[256];
    float tacc = 0.f;
    for (int t = threadIdx.x; t < CIN_ * 4; t += 256) {
        int c = t >> 2, d = t & 3;
        float mean = stats3[c] * inv_n;
        float var  = stats3[192 + c] * inv_n - mean * mean;
        float sc   = g3[c] / sqrtf(var + EPS_);
        float tc   = b3[c] - mean * sc;
        float wv   = Wc[(size_t)o * (CIN_ * 4) + t];
        float w    = sc * wv;
        unsigned int u = __float_as_uint(w);
        float rr = w - __uint_as_float(u & 0xFFFF0000u);
        int f  = d * CIN_ + c;                 // GEMM k index
        int ks = f >> 5, j = f & 7, lg = (f >> 3) & 3;
        size_t fi = ((size_t)(ks * 16 + (o >> 4)) * 64 + (lg * 16 + (o & 15))) * 8 + j;
        Wh[fi] = (unsigned short)(u >> 16);
        Wl[fi] = (unsigned short)(__float_as_uint(rr) >> 16);
        tacc += tc * wv;
    }
    red[threadIdx.x] = tacc;
    __syncthreads();
    for (int s = 128; s; s >>= 1) {
        if (threadIdx.x < s) red[threadIdx.x] += red[threadIdx.x + s];
        __syncthreads();
    }
    if (threadIdx.x == 0) bcp[o] = bc[o] + red[0];
}

// ---------------- conv: MFMA GEMM 16384x768 @ 768x256, bf16x3 ----------------
__global__ __launch_bounds__(512) void conv_kernel(const float* __restrict__ xp,
                                                   const unsigned short* __restrict__ Wh,
                                                   const unsigned short* __restrict__ Wl,
                                                   const float* __restrict__ bcp,
                                                   float* __restrict__ out) {
    __shared__ __align__(16) unsigned short Ah_s[64 * 64];      // 8 KB
    __shared__ __align__(16) unsigned short Al_s[64 * 64];      // 8 KB
    __shared__ __align__(16) unsigned short Bh_s[2 * 16 * 64 * 8]; // 32 KB
    __shared__ __align__(16) unsigned short Bl_s[2 * 16 * 64 * 8]; // 32 KB

    const int tid  = threadIdx.x;
    const int lane = tid & 63;
    const int wid  = tid >> 6;
    const int wr   = wid >> 2;          // 0..1: 32-row half
    const int wc   = wid & 3;           // 0..3: 64-col quarter
    const int row0 = blockIdx.x * 64;

    f32x4 acc[2][4];
    #pragma unroll
    for (int i = 0; i < 2; ++i)
        #pragma unroll
        for (int n = 0; n < 4; ++n) acc[i][n] = (f32x4){0.f, 0.f, 0.f, 0.f};

    const int ar  = tid >> 3;
    const int akq = tid & 7;
    const int a_byte = ar * 128 + ((akq ^ (ar & 7)) << 4);
    const float* arow = xp + (size_t)(row0 + ar) * 768 + akq * 8;

    const int fr_row = lane & 15;
    const int fr_grp = lane >> 4;       // k-subgroup 0..3

    for (int ks2 = 0; ks2 < 12; ++ks2) {
        __syncthreads();
        {
            const float* p = arow + ks2 * 64;
            float4 v0 = *(const float4*)p;
            float4 v1 = *(const float4*)(p + 4);
            uint4 h4, l4;
            h4.x = pack_hi(v0.x, v0.y); h4.y = pack_hi(v0.z, v0.w);
            h4.z = pack_hi(v1.x, v1.y); h4.w = pack_hi(v1.z, v1.w);
            l4.x = pack_lo(v0.x, v0.y); l4.y = pack_lo(v0.z, v0.w);
            l4.z = pack_lo(v1.x, v1.y); l4.w = pack_lo(v1.z, v1.w);
            *(uint4*)((char*)Ah_s + a_byte) = h4;
            *(uint4*)((char*)Al_s + a_byte) = l4;
        }
        {
            const uint4* gh = (const uint4*)(Wh + (size_t)ks2 * 16384);
            const uint4* gl = (const uint4*)(Wl + (size_t)ks2 * 16384);
            uint4* lh = (uint4*)Bh_s;
            uint4* ll = (uint4*)Bl_s;
            #pragma unroll
            for (int i = 0; i < 4; ++i) {
                lh[tid + 512 * i] = gh[tid + 512 * i];
                ll[tid + 512 * i] = gl[tid + 512 * i];
            }
        }
        __syncthreads();
        #pragma unroll
        for (int ks = 0; ks < 2; ++ks) {
            bf16x8 ah[2], al[2];
            #pragma unroll
            for (int i = 0; i < 2; ++i) {
                int r = wr * 32 + i * 16 + fr_row;
                int slot = ks * 4 + fr_grp;
                int byte = r * 128 + ((slot ^ (r & 7)) << 4);
                ah[i] = *(const bf16x8*)((const char*)Ah_s + byte);
                al[i] = *(const bf16x8*)((const char*)Al_s + byte);
            }
            #pragma unroll
            for (int nt = 0; nt < 4; ++nt) {
                int bidx = ((ks * 16 + wc * 4 + nt) * 64 + lane) * 8;
                bf16x8 bh = *(const bf16x8*)(Bh_s + bidx);
                bf16x8 bl = *(const bf16x8*)(Bl_s + bidx);
                #pragma unroll
                for (int i = 0; i < 2; ++i) {
                    acc[i][nt] = __builtin_amdgcn_mfma_f32_16x16x32_bf16(ah[i], bh, acc[i][nt], 0, 0, 0);
                    acc[i][nt] = __builtin_amdgcn_mfma_f32_16x16x32_bf16(ah[i], bl, acc[i][nt], 0, 0, 0);
                    acc[i][nt] = __builtin_amdgcn_mfma_f32_16x16x32_bf16(al[i], bh, acc[i][nt], 0, 0, 0);
                }
            }
        }
    }

    float bias[4];
    #pragma unroll
    for (int nt = 0; nt < 4; ++nt) bias[nt] = bcp[wc * 64 + nt * 16 + fr_row];
    #pragma unroll
    for (int i = 0; i < 2; ++i) {
        #pragma unroll
        for (int nt = 0; nt < 4; ++nt) {
            int col = wc * 64 + nt * 16 + fr_row;
            #pragma unroll
            for (int rg = 0; rg < 4; ++rg) {
                int row = row0 + wr * 32 + i * 16 + fr_grp * 4 + rg;
                out[(size_t)row * F2_ + col] = fmaxf(acc[i][nt][rg] + bias[nt], 0.0f);
            }
        }
    }
}

extern "C" void kernel_launch(void* const* d_in, const int* in_sizes, int n_in,
                              void* d_out, int out_size, void* d_ws, size_t ws_size,
                              hipStream_t stream) {
    const float* points  = (const float*)d_in[0];
    const float* queries = (const float*)d_in[1];
    const float* prev    = (const float*)d_in[2];
    const float* g1 = (const float*)d_in[3];
    const float* b1 = (const float*)d_in[4];
    const float* W1 = (const float*)d_in[5];
    const float* c1 = (const float*)d_in[6];
    const float* g2 = (const float*)d_in[7];
    const float* b2 = (const float*)d_in[8];
    const float* W2 = (const float*)d_in[9];
    const float* c2 = (const float*)d_in[10];
    const float* g3 = (const float*)d_in[11];
    const float* b3 = (const float*)d_in[12];
    const float* Wc = (const float*)d_in[13];
    const float* bc = (const float*)d_in[14];
    float* out = (float*)d_out;

    // Workspace layout (~59.5 MB; aliases are stream-order-safe):
    char* ws = (char*)d_ws;
    size_t off_idx    = 0;                               // 2,097,152 B
    size_t off_local  = off_idx + (size_t)NQ_*K_*4;      // 6,291,456 B (dead after h2pool)
    size_t off_stats3 = off_local + (size_t)NROWS_*3*4;  // 4,096 B (384 f32)
    size_t off_W1p    = off_stats3 + 4096;               // 512 B
    size_t off_c1p    = off_W1p + 512;                   // 512 B
    size_t off_W2p    = off_c1p + 512;                   // 8,192 B
    size_t off_c2p    = off_W2p + 8192;                  // 512 B
    size_t off_Wt     = off_c2p + 512;                   // 786,432 B: Wh(393216)+Wl(393216)
    size_t off_bcp    = off_Wt + 786432;                 // 1,024 B
    size_t off_xp     = off_bcp + 1024;                  // 50,331,648 B

    int*   idx    = (int*)(ws + off_idx);
    float* local  = (float*)(ws + off_local);
    float* stats3 = (float*)(ws + off_stats3);
    float* W1p    = (float*)(ws + off_W1p);
    float* c1p    = (float*)(ws + off_c1p);
    float* W2p    = (float*)(ws + off_W2p);
    float* c2p    = (float*)(ws + off_c2p);
    unsigned short* Wh = (unsigned short*)(ws + off_Wt);
    unsigned short* Wl = (unsigned short*)(ws + off_Wt + 393216);
    float* bcp    = (float*)(ws + off_bcp);
    float* xp     = (float*)(ws + off_xp);
    // part1 (64 KB) + part2 (512*64 f32 = 128 KB) alias the Wh/Wl region:
    // consumed by fold1/fold2 BEFORE fold3 writes Wh/Wl.
    float* part1  = (float*)(ws + off_Wt);
    float* part2  = (float*)(ws + off_Wt + 65536);
    // part3 (512*384 f32 = 768 KB) aliases local: written by stats3 AFTER
    // h2pool's last read of local.
    float* part3  = (float*)(ws + off_local);

    knn_kernel<<<NQ_ / 8, 512, 0, stream>>>(points, queries, idx, local, part1);
    fold1_kernel<<<1, 256, 0, stream>>>(part1, g1, b1, W1, c1, W1p, c1p);
    stats2_kernel<<<S2_BLK, 256, 0, stream>>>(local, W1p, c1p, part2);
    fold2_kernel<<<1, 128, 0, stream>>>(part2, g2, b2, W2, c2, W2p, c2p);
    h2pool_kernel<<<NQ_ / 4, 256, 0, stream>>>(local, W1p, c1p, W2p, c2p, xp);
    gatherpool_kernel<<<NQ_ / 4, 256, 0, stream>>>(idx, prev, xp);
    stats3_kernel<<<S3_BLK, 192, 0, stream>>>(xp, part3);
    finalize3_kernel<<<1, 384, 0, stream>>>(part3, stats3);
    fold3_kernel<<<F2_, 256, 0, stream>>>(stats3, g3, b3, Wc, bc, Wh, Wl, bcp);
    conv_kernel<<<NQ_ / 64, 512, 0, stream>>>(xp, Wh, Wl, bcp, out);
}